// Round 8
// baseline (20313.133 us; speedup 1.0000x reference)
//
#include <hip/hip_runtime.h>
#include <hip/hip_bf16.h>
#include <stdint.h>

// Problem dims
#define B_   16
#define T_   4096
#define F_   47
#define HID_ 64
#define CH_  256
#define TG_  1024   // T/4
#define G3_  768    // 3*CH

using bf16x8 = __attribute__((ext_vector_type(8))) short;  // 8 bf16 (4 VGPRs)
using bf16x4 = __attribute__((ext_vector_type(4))) short;  // 4 bf16 (2 VGPRs)
using f32x4  = __attribute__((ext_vector_type(4))) float;  // 4 fp32 acc
using f16x8  = __attribute__((ext_vector_type(8))) _Float16;

__device__ __forceinline__ short f2bf(float f) {
    union { float f; uint32_t u; } v; v.f = f;
    uint32_t u = v.u;
    uint32_t r = (u + 0x7fffu + ((u >> 16) & 1u)) >> 16;   // RNE
    return (short)r;
}
__device__ __forceinline__ float bf2f(short s) {
    union { uint32_t u; float f; } v; v.u = ((uint32_t)(uint16_t)s) << 16;
    return v.f;
}
__device__ __forceinline__ float fast_tanh(float x) {
    float e = __expf(2.f * x);           // inf-safe
    return 1.f - 2.f / (e + 1.f);
}
__device__ __forceinline__ float fast_sigmoid(float x) {
    return 1.f / (1.f + __expf(-x));
}
__device__ __forceinline__ f16x8 cvt8(const float* p) {
    float4 x = *(const float4*)p, y = *(const float4*)(p + 4);
    f16x8 f;
    f[0] = (_Float16)x.x; f[1] = (_Float16)x.y;
    f[2] = (_Float16)x.z; f[3] = (_Float16)x.w;
    f[4] = (_Float16)y.x; f[5] = (_Float16)y.y;
    f[6] = (_Float16)y.z; f[7] = (_Float16)y.w;
    return f;
}

// ---------------------------------------------------------------------------
// K1: conv1 (pointwise 47->64) + tanh, fp32 VALU, writes c1 as bf16
__global__ __launch_bounds__(256) void k1_conv1(const float* __restrict__ feat,
        const float* __restrict__ W1, const float* __restrict__ b1,
        short* __restrict__ c1) {
    __shared__ float sW[47 * 64];
    __shared__ float sF[4 * 47];
    int tid = threadIdx.x;
    int b = blockIdx.x >> 10, t0 = (blockIdx.x & 1023) * 4;
    if (tid < 188) sF[tid] = feat[((size_t)b * T_ + t0) * 47 + tid];
    for (int i = tid; i < 47 * 64; i += 256) {
        int f = i >> 6, h = i & 63;
        sW[i] = W1[h * 47 + f];
    }
    __syncthreads();
    int fr = tid >> 6, h = tid & 63;
    float acc = b1[h];
    #pragma unroll
    for (int f = 0; f < 47; ++f)
        acc += sF[fr * 47 + f] * sW[f * 64 + h];
    c1[((size_t)b * T_ + t0 + fr) * 64 + h] = f2bf(fast_tanh(acc));
}

// ---------------------------------------------------------------------------
// Weight prep (bf16 B^T layouts for the prelude GEMMs)
__global__ __launch_bounds__(256) void k_prep(const float* __restrict__ W2,
        const float* __restrict__ Wt, const float* __restrict__ Wih_f,
        short* __restrict__ W2t, short* __restrict__ Wtt, short* __restrict__ Wih) {
    int idx = blockIdx.x * 256 + threadIdx.x;
    if (idx < 256 * 512) {
        int o = idx >> 9, i = idx & 511, d = i >> 8, jj = i & 255;
        W2t[idx] = f2bf(W2[(size_t)o * 512 + jj * 2 + d]);
    }
    {
        int n = idx >> 8, ic = idx & 255, o = n & 255, kp = n >> 8;
        Wtt[idx] = f2bf(Wt[(size_t)ic * 1024 + o * 4 + kp]);
    }
    if (idx < G3_ * CH_)
        Wih[idx] = f2bf(Wih_f[idx]);
}

// ---------------------------------------------------------------------------
// K2: conv2 (k=2 causal) as GEMM M=16384,K=512,N=256 + tanh.
__global__ __launch_bounds__(256) void k2_conv2(const short* __restrict__ c1,
        const short* __restrict__ W2t, const float* __restrict__ b2,
        short* __restrict__ y2) {
    int tid = threadIdx.x, w = tid >> 6, l = tid & 63;
    int lane16 = l & 15, quad = l >> 4;
    int mt = blockIdx.x * 4 + w;
    int row = mt * 16 + lane16;
    int tg = row & 1023;
    const short* Arow = c1 + (size_t)row * 256 - 256;
    bf16x8 zero8 = {0,0,0,0,0,0,0,0};
    bf16x8 af[16];
    #pragma unroll
    for (int kt = 0; kt < 16; ++kt) {
        int i0 = kt * 32 + quad * 8;
        bool masked = (tg == 0) && (kt < 8);
        const short* p = masked ? c1 : (Arow + i0);
        bf16x8 v = *(const bf16x8*)p;
        af[kt] = masked ? zero8 : v;
    }
    #pragma unroll
    for (int nt = 0; nt < 16; ++nt) {
        int n = nt * 16 + lane16;
        f32x4 acc = {0.f, 0.f, 0.f, 0.f};
        const short* Brow = W2t + (size_t)n * 512 + quad * 8;
        #pragma unroll
        for (int kt = 0; kt < 16; ++kt) {
            bf16x8 bf = *(const bf16x8*)(Brow + kt * 32);
            acc = __builtin_amdgcn_mfma_f32_16x16x32_bf16(af[kt], bf, acc, 0, 0, 0);
        }
        float bias = b2[n];
        #pragma unroll
        for (int r = 0; r < 4; ++r) {
            int mrow = mt * 16 + quad * 4 + r;
            y2[(size_t)mrow * 256 + n] = f2bf(fast_tanh(acc[r] + bias));
        }
    }
}

// ---------------------------------------------------------------------------
// K3a: tconv as GEMM M=16384,K=256,N=1024 + tanh -> c3 bf16.
__global__ __launch_bounds__(256) void k3a_tconv(const short* __restrict__ y2,
        const short* __restrict__ Wtt, const float* __restrict__ bt,
        short* __restrict__ c3) {
    int tid = threadIdx.x, w = tid >> 6, l = tid & 63;
    int lane16 = l & 15, quad = l >> 4;
    int mt = blockIdx.x;
    int row = mt * 16 + lane16;
    const short* Arow = y2 + (size_t)row * 256 + quad * 8;
    bf16x8 af[8];
    #pragma unroll
    for (int kt = 0; kt < 8; ++kt) af[kt] = *(const bf16x8*)(Arow + kt * 32);
    #pragma unroll
    for (int nt2 = 0; nt2 < 16; ++nt2) {
        int n = (w * 16 + nt2) * 16 + lane16;
        f32x4 acc = {0.f, 0.f, 0.f, 0.f};
        const short* Brow = Wtt + (size_t)n * 256 + quad * 8;
        #pragma unroll
        for (int kt = 0; kt < 8; ++kt) {
            bf16x8 bf = *(const bf16x8*)(Brow + kt * 32);
            acc = __builtin_amdgcn_mfma_f32_16x16x32_bf16(af[kt], bf, acc, 0, 0, 0);
        }
        int kp = n >> 8, o = n & 255;
        float bias = bt[o];
        #pragma unroll
        for (int r = 0; r < 4; ++r) {
            int mrow = mt * 16 + quad * 4 + r;
            int bb = mrow >> 10, tgg = mrow & 1023;
            c3[(((size_t)bb * TG_ + tgg) * 4 + kp) * 256 + o] =
                f2bf(fast_tanh(acc[r] + bias));
        }
    }
}

// ---------------------------------------------------------------------------
// K3b: x-projection GEMM M=65536,K=256,N=768 (+b_ih) -> gates bf16.
// gates[(b*T+t)*768 + n]
__global__ __launch_bounds__(256) void k3b_xproj(const short* __restrict__ c3,
        const short* __restrict__ Wih, const float* __restrict__ b_ih,
        short* __restrict__ gates) {
    int tid = threadIdx.x, w = tid >> 6, l = tid & 63;
    int lane16 = l & 15, quad = l >> 4;
    int mt = blockIdx.x;
    int row = mt * 16 + lane16;
    const short* Arow = c3 + (size_t)row * 256 + quad * 8;
    bf16x8 af[8];
    #pragma unroll
    for (int kt = 0; kt < 8; ++kt) af[kt] = *(const bf16x8*)(Arow + kt * 32);
    #pragma unroll
    for (int nt2 = 0; nt2 < 12; ++nt2) {
        int n = (w * 12 + nt2) * 16 + lane16;
        f32x4 acc = {0.f, 0.f, 0.f, 0.f};
        const short* Brow = Wih + (size_t)n * 256 + quad * 8;
        #pragma unroll
        for (int kt = 0; kt < 8; ++kt) {
            bf16x8 bf = *(const bf16x8*)(Brow + kt * 32);
            acc = __builtin_amdgcn_mfma_f32_16x16x32_bf16(af[kt], bf, acc, 0, 0, 0);
        }
        float bias = b_ih[n];
        #pragma unroll
        for (int r = 0; r < 4; ++r) {
            int mrow = mt * 16 + quad * 4 + r;
            gates[(size_t)mrow * G3_ + n] = f2bf(acc[r] + bias);
        }
    }
}

// ---------------------------------------------------------------------------
// K4: BATCHED-16 persistent GRU on the matrix pipe — ONE block, 512 thr.
// Insight: B=16 independent sequences fill mfma_f32_16x16x32_f16's N=16
// exactly. Per step, GEMM M=768 K=256 N=16 = 384 MFMA on ONE CU serves ALL
// batches: 96 MFMA/SIMD x 19.4cy = 1862 cy/step (vs r0: 2786 cy/step per
// batch, r7 broadcast: 15/16 wasted).
// Layouts (validated in r1): A-frag lane=(quad,l16): A[row=l16][k=quad*8+e];
// B-frag: B[k=quad*8+e][col=l16] = h[batch=l16][k]; D: row=quad*4+r, col=l16.
// Wave w owns tiles {m,16+m,32+m} for m in {w,8+w} -> after the MFMA chain
// each lane holds the COMPLETE r,z,n sums for channels {16w+4q..+4,
// 128+16w+4q..+4} x batch=l16 -> elementwise fully IN-REGISTER: no part[],
// no cross-wave reduce, ONE barrier/step. h_old for (b,ch) stays in regs
// (same lane owns it every step). Gates: 6x8B coalesced loads per lane per
// step, issued at step top, latency hidden under the MFMA phase.
// h in LDS [2][16][264] f16 (264-pad -> B-frag reads 2-way-bank = free).
// Registers: 192 A-frag regs -> AGPRs (MFMA-native, tax-free home, proven
// in r1); ~120 working set <= 128 arch at launch_bounds(512,2).
__global__ __launch_bounds__(512, 2) void k4_gru_bat(const float* __restrict__ W_hh,
        const float* __restrict__ b_hh, const short* __restrict__ gates,
        float* __restrict__ out) {
    __shared__ __align__(16) _Float16 h_s[2][16][264];   // 16.5KB, padded rows

    int tid = threadIdx.x, l = tid & 63, w = tid >> 6;   // w in 0..7
    int bat = l & 15, quad = l >> 4;
    int chA = w * 16 + quad * 4;          // set A channels chA..chA+3
    int chB = 128 + chA;                  // set B

    // ---- persistent A-fragments (one-time, fp32 source): 6 x 8 x 4 = 192 regs
    f16x8 aRA[8], aZA[8], aNA[8], aRB[8], aZB[8], aNB[8];
    {
        const float* pRA = W_hh + (size_t)(      w * 16 + bat) * 256;
        const float* pZA = W_hh + (size_t)(256 + w * 16 + bat) * 256;
        const float* pNA = W_hh + (size_t)(512 + w * 16 + bat) * 256;
        const float* pRB = W_hh + (size_t)(128 + w * 16 + bat) * 256;
        const float* pZB = W_hh + (size_t)(384 + w * 16 + bat) * 256;
        const float* pNB = W_hh + (size_t)(640 + w * 16 + bat) * 256;
        #pragma unroll
        for (int kt = 0; kt < 8; ++kt) {
            int off = kt * 32 + quad * 8;
            aRA[kt] = cvt8(pRA + off);
            aZA[kt] = cvt8(pZA + off);
            aNA[kt] = cvt8(pNA + off);
            aRB[kt] = cvt8(pRB + off);
            aZB[kt] = cvt8(pZB + off);
            aNB[kt] = cvt8(pNB + off);
        }
    }

    // ---- biases for this lane's 8 channels (16B-aligned vector loads)
    f32x4 bRA = *(const f32x4*)(b_hh + chA);
    f32x4 bZA = *(const f32x4*)(b_hh + 256 + chA);
    f32x4 bNA = *(const f32x4*)(b_hh + 512 + chA);
    f32x4 bRB = *(const f32x4*)(b_hh + chB);
    f32x4 bZB = *(const f32x4*)(b_hh + 256 + chB);
    f32x4 bNB = *(const f32x4*)(b_hh + 512 + chB);

    f32x4 hA = {0.f, 0.f, 0.f, 0.f}, hB = {0.f, 0.f, 0.f, 0.f};  // h_old in regs

    // ---- h_s[0] = 0
    {
        short* hz = (short*)&h_s[0][0][0];
        for (int i = tid; i < 16 * 264; i += 512) hz[i] = 0;
    }
    __syncthreads();

    const short* gp = gates + (size_t)bat * T_ * G3_;   // this lane's batch row
    float* op = out + (size_t)bat * T_ * CH_;

    for (int s = 0; s < T_; ++s) {
        // ---- gate prefetch (6 x 8B, coalesced; latency hides under MFMA)
        const short* g0 = gp + (size_t)s * G3_;
        bf16x4 gra = *(const bf16x4*)(g0 + chA);
        bf16x4 gza = *(const bf16x4*)(g0 + 256 + chA);
        bf16x4 gna = *(const bf16x4*)(g0 + 512 + chA);
        bf16x4 grb = *(const bf16x4*)(g0 + chB);
        bf16x4 gzb = *(const bf16x4*)(g0 + 256 + chB);
        bf16x4 gnb = *(const bf16x4*)(g0 + 512 + chB);

        // ---- MFMA phase: 48 MFMA/wave, one shared B-frag per kt
        const _Float16* hrow = &h_s[s & 1][bat][0];
        f32x4 accRA = {0.f,0.f,0.f,0.f}, accZA = {0.f,0.f,0.f,0.f},
              accNA = {0.f,0.f,0.f,0.f}, accRB = {0.f,0.f,0.f,0.f},
              accZB = {0.f,0.f,0.f,0.f}, accNB = {0.f,0.f,0.f,0.f};
        #pragma unroll
        for (int kt = 0; kt < 8; ++kt) {
            f16x8 hb = *(const f16x8*)(hrow + kt * 32 + quad * 8);
            accRA = __builtin_amdgcn_mfma_f32_16x16x32_f16(aRA[kt], hb, accRA, 0, 0, 0);
            accZA = __builtin_amdgcn_mfma_f32_16x16x32_f16(aZA[kt], hb, accZA, 0, 0, 0);
            accNA = __builtin_amdgcn_mfma_f32_16x16x32_f16(aNA[kt], hb, accNA, 0, 0, 0);
            accRB = __builtin_amdgcn_mfma_f32_16x16x32_f16(aRB[kt], hb, accRB, 0, 0, 0);
            accZB = __builtin_amdgcn_mfma_f32_16x16x32_f16(aZB[kt], hb, accZB, 0, 0, 0);
            accNB = __builtin_amdgcn_mfma_f32_16x16x32_f16(aNB[kt], hb, accNB, 0, 0, 0);
        }

        // ---- elementwise fully in-register (8 instances/lane)
        union { _Float16 h4[4]; uint64_t u8; } hpA, hpB;
        f32x4 ovA, ovB;
        #pragma unroll
        for (int r = 0; r < 4; ++r) {
            float rr = fast_sigmoid(bf2f(gra[r]) + accRA[r] + bRA[r]);
            float zz = fast_sigmoid(bf2f(gza[r]) + accZA[r] + bZA[r]);
            float nn = fast_tanh(bf2f(gna[r]) + rr * (accNA[r] + bNA[r]));
            float hv = (1.f - zz) * nn + zz * hA[r];
            hA[r] = hv; hpA.h4[r] = (_Float16)hv; ovA[r] = hv;

            float rr2 = fast_sigmoid(bf2f(grb[r]) + accRB[r] + bRB[r]);
            float zz2 = fast_sigmoid(bf2f(gzb[r]) + accZB[r] + bZB[r]);
            float nn2 = fast_tanh(bf2f(gnb[r]) + rr2 * (accNB[r] + bNB[r]));
            float hv2 = (1.f - zz2) * nn2 + zz2 * hB[r];
            hB[r] = hv2; hpB.h4[r] = (_Float16)hv2; ovB[r] = hv2;
        }
        _Float16* hn = &h_s[(s + 1) & 1][bat][0];
        *(uint64_t*)(hn + chA) = hpA.u8;
        *(uint64_t*)(hn + chB) = hpB.u8;

        // ---- output stores (16B each; 64B contiguous per batch per wave)
        float* o0 = op + (size_t)s * CH_;
        *(f32x4*)(o0 + chA) = ovA;
        *(f32x4*)(o0 + chB) = ovB;

        __syncthreads();   // one barrier per step: h_s[(s+1)&1] complete
    }
}

// ---------------------------------------------------------------------------
extern "C" void kernel_launch(void* const* d_in, const int* in_sizes, int n_in,
                              void* d_out, int out_size, void* d_ws, size_t ws_size,
                              hipStream_t stream) {
    const float* feat  = (const float*)d_in[0];
    const float* W1    = (const float*)d_in[1];
    const float* b1    = (const float*)d_in[2];
    const float* W2    = (const float*)d_in[3];
    const float* b2    = (const float*)d_in[4];
    const float* Wt    = (const float*)d_in[5];
    const float* bt    = (const float*)d_in[6];
    const float* Wih_f = (const float*)d_in[7];
    const float* Whh   = (const float*)d_in[8];
    const float* bih   = (const float*)d_in[9];
    const float* bhh   = (const float*)d_in[10];
    float* out = (float*)d_out;

    // ws layout (135.4 MB):
    //   [0, 33.5M)      c3 bf16 (c1 aliases first 8.4M; c1 dead after K2)
    //   [33.5M, 134.2M) gates bf16 (y2 aliases first 8.4M; y2 dead after K3a)
    //   [134.2M, ...)   W2t / Wtt / Wih bf16
    char* ws = (char*)d_ws;
    short* c3    = (short*)(ws);
    short* c1    = (short*)(ws);
    short* gates = (short*)(ws + 33554432);
    short* y2    = (short*)(ws + 33554432);
    short* W2t   = (short*)(ws + 134217728);
    short* Wtt   = (short*)(ws + 134217728 + 262144);
    short* Wih   = (short*)(ws + 134217728 + 262144 + 524288);

    k1_conv1  <<<16384, 256, 0, stream>>>(feat, W1, b1, c1);
    k_prep    <<<1024, 256, 0, stream>>>(W2, Wt, Wih_f, W2t, Wtt, Wih);
    k2_conv2  <<<256,  256, 0, stream>>>(c1, W2t, b2, y2);
    k3a_tconv <<<1024, 256, 0, stream>>>(y2, Wtt, bt, c3);      // kills c1
    k3b_xproj <<<4096, 256, 0, stream>>>(c3, Wih, bih, gates);  // kills y2
    k4_gru_bat<<<1,    512, 0, stream>>>(Whh, bhh, gates, out);
}